// Round 9
// baseline (48.910 us; speedup 1.0000x reference)
//
#include <hip/hip_runtime.h>
#include <hip/hip_bf16.h>

// Problem constants (fixed by the reference's setup_inputs)
#define BB 2
#define CC 256      // channels per level
#define HH 100      // roi-align grid (upsampled batch) H == W
#define NN 256      // rois per batch
#define KK (BB*NN)  // 512 total rois
#define C3 (3*CC)   // 768 fused channels
#define OUTB 7
#define SR 2
#define NSAMP (OUTB*SR)
#define BINS (OUTB*OUTB)  // 49
#define NP0 10000   // positions per level
#define NP1 2500
#define NP2 625
#define CQL 32      // uint4 (8 bf16 ch) per position in a 256-ch level buffer

typedef float f32x2 __attribute__((ext_vector_type(2)));

__device__ __forceinline__ unsigned int f2bf(float f) {      // RNE f32->bf16 bits
    unsigned int b = __float_as_uint(f);
    return (b + 0x7FFFu + ((b >> 16) & 1u)) >> 16;
}
__device__ __forceinline__ float bf_lo(unsigned int u) { return __uint_as_float(u << 16); }
__device__ __forceinline__ float bf_hi(unsigned int u) { return __uint_as_float(u & 0xFFFF0000u); }
__device__ __forceinline__ f32x2 upk(unsigned int u) {
    f32x2 r; r.x = bf_lo(u); r.y = bf_hi(u); return r;
}

// ---------------------------------------------------------------------------
// transpose_all: NCHW -> NHWC bf16 for all three levels (no upsample!).
// The 2x/4x bilinear upsample is folded into roi9's composed weights.
// ---------------------------------------------------------------------------
__global__ __launch_bounds__(256) void transpose_all(const float* __restrict__ x0,
                                                     const float* __restrict__ x1,
                                                     const float* __restrict__ x2,
                                                     unsigned int* __restrict__ F0,
                                                     unsigned int* __restrict__ F1,
                                                     unsigned int* __restrict__ F2) {
    __shared__ float tile[64][68];           // 16B-aligned rows
    const int bx  = blockIdx.x;              // 0..206: 157 lvl0 | 40 lvl1 | 10 lvl2
    const int cbase = blockIdx.y * 64;       // channel tile
    const int b   = blockIdx.z;
    const int tid = threadIdx.x;

    const float* src; unsigned int* dst; int npos, ptile;
    if (bx < 157)      { src = x0; dst = F0; npos = NP0; ptile = bx; }
    else if (bx < 197) { src = x1; dst = F1; npos = NP1; ptile = bx - 157; }
    else               { src = x2; dst = F2; npos = NP2; ptile = bx - 197; }

    const int f  = tid & 15;                 // pos quad
    const int cr = tid >> 4;                 // channel row
    const int p4 = ptile*64 + f*4;
    const float* p = src + (size_t)b*CC*npos;
    #pragma unroll
    for (int r = 0; r < 4; ++r) {
        int c_local = r*16 + cr;
        const float* q = p + (size_t)(cbase + c_local)*npos;
        if (p4 + 3 < npos) {
            *(float4*)&tile[c_local][f*4] = *(const float4*)(q + p4);
        } else {
            #pragma unroll
            for (int j = 0; j < 4; ++j)
                tile[c_local][f*4+j] = (p4 + j < npos) ? q[p4+j] : 0.0f;
        }
    }
    __syncthreads();

    #pragma unroll
    for (int r = 0; r < 4; ++r) {
        int p_local = r*16 + (tid >> 4);
        int pp = ptile*64 + p_local;
        if (pp < npos) {
            int c4 = (tid & 15) * 4;
            uint2 v;
            v.x = f2bf(tile[c4+0][p_local]) | (f2bf(tile[c4+1][p_local]) << 16);
            v.y = f2bf(tile[c4+2][p_local]) | (f2bf(tile[c4+3][p_local]) << 16);
            *(uint2*)(dst + (((size_t)b*npos + pp)*CC + cbase + c4) / 2) = v;
        }
    }
}

// ---------------------------------------------------------------------------
// gather_bin<NY,NX>: static-footprint composed gather (MLP = NY*NX), f32x2
// accumulators so the backend can use v_pk_fma_f32.
// ---------------------------------------------------------------------------
template<int NY, int NX>
__device__ __forceinline__ void gather_bin(const uint4* __restrict__ Fb, int Ll,
                                           int ys, int xs,
                                           const float* __restrict__ wy,
                                           const float* __restrict__ wx,
                                           f32x2 acc[4]) {
    const uint4* rp[NY];
    int xo[NX];
    #pragma unroll
    for (int j = 0; j < NY; ++j)
        rp[j] = Fb + (size_t)(min(ys + j, Ll - 1) * Ll) * CQL;
    #pragma unroll
    for (int i = 0; i < NX; ++i)
        xo[i] = min(xs + i, Ll - 1) * CQL;
    uint4 u[NY][NX];
    #pragma unroll
    for (int j = 0; j < NY; ++j)
        #pragma unroll
        for (int i = 0; i < NX; ++i)
            u[j][i] = rp[j][xo[i]];
    #pragma unroll
    for (int j = 0; j < NY; ++j) {
        const float wyj = wy[j];
        #pragma unroll
        for (int i = 0; i < NX; ++i) {
            const float w_ = wyj * wx[i];
            const f32x2 w2 = {w_, w_};
            acc[0] += w2 * upk(u[j][i].x);
            acc[1] += w2 * upk(u[j][i].y);
            acc[2] += w2 * upk(u[j][i].z);
            acc[3] += w2 * upk(u[j][i].w);
        }
    }
}

// ---------------------------------------------------------------------------
// roi9: block = (roi, chunk 0..5); chunk -> (level = chunk>>1, half = chunk&1).
// Composed bilinear-upsample o roi-bilinear weights on the native source grid;
// static 4x4 footprint (3x3 at level 2 -- si range 0.75 crosses <=1 integer
// boundary -> run width <=3).  6 blocks/CU via launch bounds.
// ---------------------------------------------------------------------------
__global__ __launch_bounds__(256, 6) void roi9(const uint4* __restrict__ F0,
                                               const uint4* __restrict__ F1,
                                               const uint4* __restrict__ F2,
                                               const float* __restrict__ boxes,
                                               const float* __restrict__ ratio_hw,
                                               const float* __restrict__ offset_tl,
                                               float* __restrict__ out) {
    __shared__ float tile[8 * 16 * 51];      // 26112 B, [j][slot][51] odd stride
    __shared__ int   s_start[2][OUTB];       // [axis][bin] first src row/col
    __shared__ float s_w[2][OUTB][4];        // composed merged weights

    const int tid   = threadIdx.x;
    const int k     = blockIdx.x;            // roi 0..511
    const int chunk = blockIdx.y;            // 0..5
    const int level = chunk >> 1;
    const int half  = chunk & 1;             // 128-ch half of the level
    const int b     = k >> 8;                // N=256

    const int   Ll = (level == 0) ? 100 : (level == 1 ? 50 : 25);
    const float sl = (level == 0) ? 1.0f : (level == 1 ? 0.5f  : 0.25f);
    const float tl = (level == 0) ? 0.0f : (level == 1 ? 0.25f : 0.375f);
    const uint4* Fl = (level == 0) ? F0 : (level == 1 ? F1 : F2);
    const int   np = (level == 0) ? NP0 : (level == 1 ? NP1 : NP2);

    if (tid < 2*OUTB) {
        const int axis = tid / OUTB;         // 0 = y, 1 = x
        const int bin  = tid - axis*OUTB;
        float r0 = ratio_hw[0], o0 = offset_tl[0];
        float scale = (float)HH / (1250.0f * r0 + 2.0f * o0);
        const float* bx = boxes + (size_t)k * 4;
        float a, e;
        if (axis) { float rW = ratio_hw[2*b+1], left = offset_tl[2*b+1];
                    a = (bx[0]*rW + left)*scale; e = (bx[2]*rW + left)*scale; }
        else      { float rH = ratio_hw[2*b],   top  = offset_tl[2*b];
                    a = (bx[1]*rH + top)*scale;  e = (bx[3]*rH + top)*scale;  }
        float len = fmaxf(e - a, 1.0f);      // ALIGNED=False
        float bs = len * (1.0f / (float)OUTB);
        float w[6] = {0.f,0.f,0.f,0.f,0.f,0.f};
        int st = -1;
        #pragma unroll
        for (int s = 0; s < 2; ++s) {
            float g = (float)bin + 0.25f + 0.5f*(float)s;
            float p = a + g*bs;
            float vv = (p >= -1.0f && p <= (float)HH) ? 0.5f : 0.0f;  // 0.25 mean folded
            float cc = fminf(fmaxf(p, 0.0f), (float)(HH - 1));
            int   i0 = (int)floorf(cc);      // up-grid neighbors
            float fu = cc - (float)i0;
            int   i1 = min(i0 + 1, HH - 1);
            #pragma unroll
            for (int j = 0; j < 2; ++j) {
                int   i  = j ? i1 : i0;
                float wu = j ? vv*fu : vv*(1.0f - fu);
                float si = fminf(fmaxf((float)i*sl - tl, 0.0f), (float)(Ll - 1));
                int   a0 = (int)floorf(si);  // source-grid neighbors
                float g2 = si - (float)a0;
                int   a1 = min(a0 + 1, Ll - 1);
                if (st < 0) st = a0;         // first contribution is minimal (monotone)
                w[a0 - st] += wu*(1.0f - g2);
                w[a1 - st] += wu*g2;
            }
        }
        s_start[axis][bin] = st;
        s_w[axis][bin][0] = w[0]; s_w[axis][bin][1] = w[1];
        s_w[axis][bin][2] = w[2]; s_w[axis][bin][3] = w[3];
    }
    __syncthreads();

    const int slot = tid & 15;               // 8-bf16-channel slot within half
    const int bg   = tid >> 4;               // bin group 0..15
    const uint4* Fb = Fl + (size_t)b*np*CQL + half*16 + slot;

    #pragma unroll
    for (int t = 0; t < 4; ++t) {
        const int bin = bg + 16*t;
        if (bin < BINS) {
            const int oy = bin / OUTB;
            const int ox = bin - oy*OUTB;
            const int ys = s_start[0][oy];
            const int xs = s_start[1][ox];
            f32x2 acc[4];
            acc[0] = (f32x2)0.f; acc[1] = (f32x2)0.f;
            acc[2] = (f32x2)0.f; acc[3] = (f32x2)0.f;
            if (level == 2)
                gather_bin<3,3>(Fb, Ll, ys, xs, s_w[0][oy], s_w[1][ox], acc);
            else
                gather_bin<4,4>(Fb, Ll, ys, xs, s_w[0][oy], s_w[1][ox], acc);

            // channel c = slot*8 + (2q+h) -> tile[c8][slot][bin], stride 51
            #pragma unroll
            for (int q = 0; q < 4; ++q) {
                tile[(2*q+0)*16*51 + slot*51 + bin] = acc[q].x;
                tile[(2*q+1)*16*51 + slot*51 + bin] = acc[q].y;
            }
        }
    }
    __syncthreads();

    // One contiguous, fully-coalesced 25 KB write per block.
    // chunk -> output channel base: level*256 + half*128.
    float* dst = out + ((size_t)k*C3 + (size_t)chunk*128) * BINS;
    for (int i = tid; i < 128*BINS; i += 256) {
        const int c = i / BINS;              // local channel 0..127
        const int bin = i - c*BINS;
        dst[i] = tile[(c & 7)*16*51 + (c >> 3)*51 + bin];
    }
}

// ---------------------------------------------------------------------------
// Fallback (no workspace): direct gather from sources, one float per thread.
// ---------------------------------------------------------------------------
__device__ __forceinline__ float feat_val(const float* __restrict__ x0,
                                          const float* __restrict__ x1,
                                          const float* __restrict__ x2,
                                          int b, int y, int x, int c) {
    if (c < CC) {
        return x0[(((size_t)b*CC + c)*HH + y)*HH + x];
    }
    const float* src;
    int L; float s, t; int cl;
    if (c < 2*CC) { src = x1; L = 50; s = 0.5f;  t = 0.25f;  cl = c - CC; }
    else          { src = x2; L = 25; s = 0.25f; t = 0.375f; cl = c - 2*CC; }
    float cy = fminf(fmaxf((float)y * s - t, 0.0f), (float)(L - 1));
    float cx = fminf(fmaxf((float)x * s - t, 0.0f), (float)(L - 1));
    int yl = (int)cy, xl = (int)cx;
    int yh = min(yl + 1, L - 1), xh = min(xl + 1, L - 1);
    float fy = cy - (float)yl, fx = cx - (float)xl;
    const float* p = src + (((size_t)b*CC + cl)*L)*L;
    float v00 = p[yl*L + xl], v01 = p[yl*L + xh];
    float v10 = p[yh*L + xl], v11 = p[yh*L + xh];
    float hy = 1.0f - fy, hx = 1.0f - fx;
    return v00*(hy*hx) + v01*(hy*fx) + v10*(fy*hx) + v11*(fy*fx);
}

__global__ __launch_bounds__(256) void roi_fallback(const float* __restrict__ x0,
                                                    const float* __restrict__ x1,
                                                    const float* __restrict__ x2,
                                                    const float* __restrict__ boxes,
                                                    const float* __restrict__ ratio_hw,
                                                    const float* __restrict__ offset_tl,
                                                    float* __restrict__ out) {
    __shared__ int   s_ylo[NSAMP], s_yhi[NSAMP], s_xlo[NSAMP], s_xhi[NSAMP];
    __shared__ float s_fy[NSAMP], s_fx[NSAMP];
    __shared__ int   s_vy[NSAMP], s_vx[NSAMP];

    const int tid = threadIdx.x;
    const int k = blockIdx.x;
    const int chunk = blockIdx.y;
    const int b = k >> 8;

    if (tid < 2*NSAMP) {
        float r0 = ratio_hw[0], o0 = offset_tl[0];
        float scale = (float)HH / (1250.0f * r0 + 2.0f * o0);
        float rH  = ratio_hw[2*b],  rW   = ratio_hw[2*b + 1];
        float top = offset_tl[2*b], left = offset_tl[2*b + 1];
        const float* bx = boxes + (size_t)k * 4;
        bool isx = (tid >= NSAMP);
        int i = isx ? tid - NSAMP : tid;
        float a, e;
        if (isx) { a = (bx[0]*rW + left)*scale; e = (bx[2]*rW + left)*scale; }
        else     { a = (bx[1]*rH + top)*scale;  e = (bx[3]*rH + top)*scale;  }
        float len = fmaxf(e - a, 1.0f);
        float bs = len * (1.0f / (float)OUTB);
        float g = (float)(i >> 1) + 0.25f + 0.5f * (float)(i & 1);
        float p = a + g * bs;
        int v = (p >= -1.0f && p <= (float)HH) ? 1 : 0;
        float cc = fminf(fmaxf(p, 0.0f), (float)(HH - 1));
        int lo = (int)floorf(cc);
        int hi = min(lo + 1, HH - 1);
        float fr = cc - (float)lo;
        if (isx) { s_xlo[i] = lo; s_xhi[i] = hi; s_fx[i] = fr; s_vx[i] = v; }
        else     { s_ylo[i] = lo; s_yhi[i] = hi; s_fy[i] = fr; s_vy[i] = v; }
    }
    __syncthreads();

    const int c = chunk * 256 + tid;
    for (int oy = 0; oy < OUTB; ++oy) {
        for (int ox = 0; ox < OUTB; ++ox) {
            float acc = 0.0f;
            #pragma unroll
            for (int sy = 0; sy < SR; ++sy) {
                const int iy = oy*SR + sy;
                #pragma unroll
                for (int sx = 0; sx < SR; ++sx) {
                    const int ix = ox*SR + sx;
                    if (s_vy[iy] && s_vx[ix]) {
                        const float fy = s_fy[iy], fx = s_fx[ix];
                        const float hy = 1.0f - fy, hx = 1.0f - fx;
                        float v00 = feat_val(x0,x1,x2,b, s_ylo[iy], s_xlo[ix], c);
                        float v01 = feat_val(x0,x1,x2,b, s_ylo[iy], s_xhi[ix], c);
                        float v10 = feat_val(x0,x1,x2,b, s_yhi[iy], s_xlo[ix], c);
                        float v11 = feat_val(x0,x1,x2,b, s_yhi[iy], s_xhi[ix], c);
                        acc += v00*(hy*hx) + v01*(hy*fx) + v10*(fy*hx) + v11*(fy*fx);
                    }
                }
            }
            out[(size_t)k*C3*BINS + (size_t)c*BINS + oy*OUTB + ox] = acc * 0.25f;
        }
    }
}

extern "C" void kernel_launch(void* const* d_in, const int* in_sizes, int n_in,
                              void* d_out, int out_size, void* d_ws, size_t ws_size,
                              hipStream_t stream) {
    const float* x0       = (const float*)d_in[0];
    const float* x1       = (const float*)d_in[1];
    const float* x2       = (const float*)d_in[2];
    const float* boxes    = (const float*)d_in[3];
    const float* ratio_hw = (const float*)d_in[4];
    const float* off_tl   = (const float*)d_in[5];
    float* out = (float*)d_out;

    const size_t needW = (size_t)(NP0 + NP1 + NP2) * BB * CC * 2;  // 13.44 MB
    if (ws_size >= needW) {
        unsigned int* F0 = (unsigned int*)d_ws;
        unsigned int* F1 = F0 + (size_t)BB*NP0*CC/2;
        unsigned int* F2 = F1 + (size_t)BB*NP1*CC/2;
        transpose_all<<<dim3(207, 4, BB), 256, 0, stream>>>(x0, x1, x2, F0, F1, F2);
        roi9<<<dim3(KK, 6), 256, 0, stream>>>((const uint4*)F0, (const uint4*)F1,
                                              (const uint4*)F2,
                                              boxes, ratio_hw, off_tl, out);
    } else {
        roi_fallback<<<dim3(KK, 3), 256, 0, stream>>>(x0, x1, x2,
                                                      boxes, ratio_hw, off_tl, out);
    }
}